// Round 18
// baseline (37.107 us; speedup 1.0000x reference)
//
#include <hip/hip_runtime.h>
#include <hip/hip_bf16.h>

// out[e] = concat(h[i0], h[i1]) @ W + b, h = logmap0(x)
// Rewritten: y[n][0:4] = h[n]·W[0:128,:] + b   (b folded here)
//            y[n][4:8] = h[n]·W[128:256,:]
//            out[e][c] = y[i0][c] + y[i1][4+c]
//
// R18 = R16 (dense lane-consecutive staging -> LDS, 8-lane/node compute)
// with ONE change: staging loads are NONTEMPORAL. x has zero reuse (read
// once, each 128B line consumed whole by one instruction), so nt costs
// nothing and skips L2/L3 allocation on the cold stream — testing whether
// allocation overhead is the 2.8 TB/s cold-read wall. R5's nt regression
// was the scattered pattern (inter-instruction line reuse); dense has none.

#define DIM 128

typedef float f32x4 __attribute__((ext_vector_type(4)));
typedef int   i32x2 __attribute__((ext_vector_type(2)));

__global__ __launch_bounds__(256) void node_proj_kernel(
    const float* __restrict__ x, const float* __restrict__ W,
    const float* __restrict__ b, float* __restrict__ y, int n_nodes)
{
    __shared__ f32x4 xs[32 * 33];     // 32 rows, stride 33 (pad 1 float4)
    __shared__ float wp[1056];
    const int t = threadIdx.x;
    {
        // Pack [W[d][0:4] | W[d+128][0:4]] at f(d)=8d+4(d>>4).
        const f32x4 wv = ((const f32x4*)W)[t];        // W row t (t<256)
        const int r = t & 127, h = t >> 7;
        *(f32x4*)(wp + r * 8 + (r >> 4) * 4 + h * 4) = wv;
    }

    const int gbase = blockIdx.x * 32;

    // ---- Stage 32 rows of x: lane-consecutive float4, NONTEMPORAL ----
    const f32x4* xg = (const f32x4*)x;
#pragma unroll
    for (int s = t; s < 1024; s += 256) {
        const int row = s >> 5, c4 = s & 31;
        const int gn = gbase + row;
        f32x4 v = {0.f, 0.f, 0.f, 0.f};
        if (gn < n_nodes) v = __builtin_nontemporal_load(xg + (size_t)gn * 32 + c4);
        xs[row * 33 + c4] = v;
    }
    __syncthreads();

    // ---- Compute: 8 lanes/node, x from LDS ----
    const int lane = t & 63;
    const int li   = lane & 7;          // dim-slice owner (16 dims)
    const int g    = lane >> 3;         // node within wave
    const int r    = (t >> 6) * 8 + g;  // row in tile (0..31)
    const int n    = gbase + r;
    if (n >= n_nodes) return;

    const f32x4* xrow = &xs[r * 33 + li * 4];
    const float* wl   = wp + li * 132;  // f(16*li) = 132*li

    f32x4 xa[4];
#pragma unroll
    for (int q = 0; q < 4; ++q) xa[q] = xrow[q];

    float acc[9];
#pragma unroll
    for (int i = 0; i < 9; ++i) acc[i] = 0.f;

#pragma unroll
    for (int q = 0; q < 4; ++q) {
#pragma unroll
        for (int k = 0; k < 4; ++k) {
            const int idx = q * 4 + k;                 // 0..15
            const f32x4 wa = *(const f32x4*)(wl + idx * 8);      // W[d][0:4]
            const f32x4 wb = *(const f32x4*)(wl + idx * 8 + 4);  // W[d+128][0:4]
            const float a = xa[q][k];
            acc[0] = fmaf(a, a, acc[0]);
            acc[1] = fmaf(a, wa[0], acc[1]);
            acc[2] = fmaf(a, wa[1], acc[2]);
            acc[3] = fmaf(a, wa[2], acc[3]);
            acc[4] = fmaf(a, wa[3], acc[4]);
            acc[5] = fmaf(a, wb[0], acc[5]);
            acc[6] = fmaf(a, wb[1], acc[6]);
            acc[7] = fmaf(a, wb[2], acc[7]);
            acc[8] = fmaf(a, wb[3], acc[8]);
        }
    }

    // 3-round butterfly across the 8-lane group (xor 1,2,4).
#pragma unroll
    for (int i = 0; i < 9; ++i) {
        acc[i] += __shfl_xor(acc[i], 1, 64);
        acc[i] += __shfl_xor(acc[i], 2, 64);
        acc[i] += __shfl_xor(acc[i], 4, 64);
    }

    // li=0 writes y[n][0:4] (+bias), li=1 writes y[n][4:8].
    if (li < 2) {
        const bool second = li;

        float norm = fmaxf(sqrtf(acc[0]), 1e-15f);           // MIN_NORM
        const float aa  = fminf(norm, 1.0f - 1e-6f);         // ATANH_EPS clip
        const float art = 0.5f * log1pf(2.0f * aa / (1.0f - aa));  // artanh
        const float scale = art / norm;

        const float w0 = second ? acc[5] : acc[1];
        const float w1 = second ? acc[6] : acc[2];
        const float w2 = second ? acc[7] : acc[3];
        const float w3 = second ? acc[8] : acc[4];

        const f32x4 bv4 = *(const f32x4*)b;
        f32x4 o;
        o[0] = fmaf(w0, scale, second ? 0.f : bv4[0]);
        o[1] = fmaf(w1, scale, second ? 0.f : bv4[1]);
        o[2] = fmaf(w2, scale, second ? 0.f : bv4[2]);
        o[3] = fmaf(w3, scale, second ? 0.f : bv4[3]);

        *(f32x4*)(y + (size_t)n * 8 + li * 4) = o;
    }
}

// 1 edge per thread, exact grid (unchanged since R11).
__global__ __launch_bounds__(256) void edge_kernel(
    const int* __restrict__ idx, const float* __restrict__ y,
    float* __restrict__ out, int n_edges)
{
    const int e = blockIdx.x * blockDim.x + threadIdx.x;
    if (e >= n_edges) return;
    const i32x2 ii = __builtin_nontemporal_load((const i32x2*)idx + e);
    const f32x4 a0 = *(const f32x4*)(y + (size_t)ii[0] * 8);
    const f32x4 c0 = *(const f32x4*)(y + (size_t)ii[1] * 8 + 4);
    const f32x4 o0 = a0 + c0;
    __builtin_nontemporal_store(o0, (f32x4*)out + e);
}

extern "C" void kernel_launch(void* const* d_in, const int* in_sizes, int n_in,
                              void* d_out, int out_size, void* d_ws, size_t ws_size,
                              hipStream_t stream) {
    const float* x   = (const float*)d_in[0];
    const int*   idx = (const int*)d_in[1];
    const float* W   = (const float*)d_in[2];
    const float* b   = (const float*)d_in[3];
    float* out = (float*)d_out;

    const int n_nodes = in_sizes[0] / DIM;
    const int n_edges = in_sizes[1] / 2;

    float* y = (float*)d_ws;  // n_nodes * 8 floats = 3.2 MB

    // Node: 32 nodes/block (staged in LDS), 3125 blocks.
    const int blocks1 = (n_nodes + 31) / 32;
    node_proj_kernel<<<blocks1, 256, 0, stream>>>(x, W, b, y, n_nodes);

    // Edge: 1 edge/thread, exact grid (1M threads).
    const int blocks2 = (n_edges + 255) / 256;
    edge_kernel<<<blocks2, 256, 0, stream>>>(idx, y, out, n_edges);
}

// Round 19
// 30.610 us; speedup vs baseline: 1.2123x; 1.2123x over previous
//
#include <hip/hip_runtime.h>
#include <hip/hip_bf16.h>

// out[e] = concat(h[i0], h[i1]) @ W + b, h = logmap0(x)
// Rewritten: y[n][0:4] = h[n]·W[0:128,:] + b   (b folded here)
//            y[n][4:8] = h[n]·W[128:256,:]
//            out[e][c] = y[i0][c] + y[i1][4+c]
//
// FINAL (= R13, measured best 30.5us). Two dispatches; node = 1 node per
// 4-lane group, 16 nodes/wave (best across 6 structural families R11-R18);
// edge = 1 edge/thread, max TLP (gather-latency-bound, R10).
// Composite floor is environmental: harness poison fills (268MB/replay)
// flush+dirty the L3, pinning the cold x read at ~2.8 TB/s (8 falsified
// kernel-side hypotheses, R12-R18); warm identical compute runs 6.4 TB/s.

#define DIM 128

typedef float f32x4 __attribute__((ext_vector_type(4)));
typedef int   i32x2 __attribute__((ext_vector_type(2)));

// Lane li of a group owns dims {j*16 + li*4 + k : j=0..7, k=0..3}.
// W packed in LDS: Wp[d] = {W[d][0:4], W[d+128][0:4]} at float-offset
// d*8 + (d>>2)*4 (skew every 4 rows -> conflict-free 4-address reads).
__global__ __launch_bounds__(256) void node_proj_kernel(
    const float* __restrict__ x, const float* __restrict__ W,
    const float* __restrict__ b, float* __restrict__ y, int n_nodes)
{
    __shared__ float wp[1152];
    const int t = threadIdx.x;
    {
        const int r = t & 127, h = t >> 7;            // row, half
        const f32x4 wv = ((const f32x4*)W)[t];        // W[256][4], row t
        *(f32x4*)(wp + r * 8 + (r >> 2) * 4 + h * 4) = wv;
    }
    __syncthreads();

    const int lane = t & 63;
    const int li   = lane & 3;
    const int gid  = lane >> 2;
    const int wid  = blockIdx.x * (blockDim.x >> 6) + (t >> 6);
    const int n0   = wid * 16 + gid;            // 1 node per 4-lane group
    if (n0 >= n_nodes) return;

    const f32x4* xp0 = (const f32x4*)(x + (size_t)n0 * DIM + li * 4);
    const float* wl  = wp + li * 36;   // f(li*4) = li*32 + li*4

    float acc[9];
#pragma unroll
    for (int i = 0; i < 9; ++i) acc[i] = 0.f;

#pragma unroll
    for (int j = 0; j < 8; ++j) {
        const f32x4 a4 = xp0[j * 4];
#pragma unroll
        for (int k = 0; k < 4; ++k) {
            // d = j*16 + li*4 + k ; float-offset f(d) = li*36 + j*144 + k*8
            const f32x4 wa = *(const f32x4*)(wl + j * 144 + k * 8);
            const f32x4 wb = *(const f32x4*)(wl + j * 144 + k * 8 + 4);
            const float a = a4[k];
            acc[0] += a * a;
            acc[1] += a * wa[0];
            acc[2] += a * wa[1];
            acc[3] += a * wa[2];
            acc[4] += a * wa[3];
            acc[5] += a * wb[0];
            acc[6] += a * wb[1];
            acc[7] += a * wb[2];
            acc[8] += a * wb[3];
        }
    }

    // 2-step butterfly within each 4-lane group (xor 1,2 -> DPP quad_perm).
#pragma unroll
    for (int i = 0; i < 9; ++i) {
        acc[i] += __shfl_xor(acc[i], 1, 64);
        acc[i] += __shfl_xor(acc[i], 2, 64);
    }

    // li=0 writes y[n0][0:4] (+bias), li=1 writes y[n0][4:8]; li>=2 idle.
    if (li < 2) {
        const bool second = li;

        float norm = fmaxf(sqrtf(acc[0]), 1e-15f);           // MIN_NORM
        const float aa  = fminf(norm, 1.0f - 1e-6f);         // ATANH_EPS clip
        const float art = 0.5f * log1pf(2.0f * aa / (1.0f - aa));  // artanh
        const float scale = art / norm;

        const float w0 = second ? acc[5] : acc[1];
        const float w1 = second ? acc[6] : acc[2];
        const float w2 = second ? acc[7] : acc[3];
        const float w3 = second ? acc[8] : acc[4];

        const f32x4 bv4 = *(const f32x4*)b;
        f32x4 o;
        o[0] = w0 * scale + (second ? 0.f : bv4[0]);
        o[1] = w1 * scale + (second ? 0.f : bv4[1]);
        o[2] = w2 * scale + (second ? 0.f : bv4[2]);
        o[3] = w3 * scale + (second ? 0.f : bv4[3]);

        *(f32x4*)(y + (size_t)n0 * 8 + li * 4) = o;
    }
}

// 1 edge per thread, exact grid: maximum outstanding gathers (R10 lesson:
// gathers are latency-bound -> TLP is the lever). idx/out nontemporal
// (streaming; keeps the 3.2 MB y table L2-resident); y gathers plain.
__global__ __launch_bounds__(256) void edge_kernel(
    const int* __restrict__ idx, const float* __restrict__ y,
    float* __restrict__ out, int n_edges)
{
    const int e = blockIdx.x * blockDim.x + threadIdx.x;
    if (e >= n_edges) return;
    const i32x2 ii = __builtin_nontemporal_load((const i32x2*)idx + e);
    const f32x4 a0 = *(const f32x4*)(y + (size_t)ii[0] * 8);
    const f32x4 c0 = *(const f32x4*)(y + (size_t)ii[1] * 8 + 4);
    const f32x4 o0 = a0 + c0;
    __builtin_nontemporal_store(o0, (f32x4*)out + e);
}

extern "C" void kernel_launch(void* const* d_in, const int* in_sizes, int n_in,
                              void* d_out, int out_size, void* d_ws, size_t ws_size,
                              hipStream_t stream) {
    const float* x   = (const float*)d_in[0];
    const int*   idx = (const int*)d_in[1];
    const float* W   = (const float*)d_in[2];
    const float* b   = (const float*)d_in[3];
    float* out = (float*)d_out;

    const int n_nodes = in_sizes[0] / DIM;
    const int n_edges = in_sizes[1] / 2;

    float* y = (float*)d_ws;  // n_nodes * 8 floats = 3.2 MB

    // Node: 16 nodes/wave, 4 waves/block -> 64 nodes/block, single-shot.
    const int blocks1 = (n_nodes + 63) / 64;
    node_proj_kernel<<<blocks1, 256, 0, stream>>>(x, W, b, y, n_nodes);

    // Edge: 1 edge/thread, exact grid (1M threads).
    const int blocks2 = (n_edges + 255) / 256;
    edge_kernel<<<blocks2, 256, 0, stream>>>(idx, y, out, n_edges);
}